// Round 5
// baseline (258.819 us; speedup 1.0000x reference)
//
#include <hip/hip_runtime.h>

// WKV (RWKV v4), single fused kernel. Block = (batch b, 8-channel tile),
// all T=1024. k,v tile (64 KB) DMA'd to LDS once via global_load_lds
// (fire-and-forget; immune to compiler load-sinking), consumed twice:
//   phase 1: 256 threads = 8 ch x 32 chunks, local scan of 32 steps each
//   phase 2: serial combine of 32 chunk states per channel (8 lanes)
//   phase 3: rescan each chunk with its true initial state, emit y
// Global traffic: 128 MB read + 64 MB write = theoretical floor.
//
// LDS chunk regions padded by 8 floats (one global_load_lds_dwordx4 per
// (chunk,tensor) = 1 KB contiguous; pad lives between instruction bases) so
// scan reads are 2-way bank aliased only (free on CDNA4).

#define T_FIX   1024
#define CHB     8                   // channels per block
#define NCHK    32                  // chunks per channel
#define CHL     (T_FIX / NCHK)      // 32 steps per chunk
#define CHUNK_F 264                 // 256 data floats + 8 pad per chunk region
#define VOFF    (NCHK * CHUNK_F)    // 8448 floats: v region offset

typedef const float __attribute__((address_space(1))) gfloat;
typedef float       __attribute__((address_space(3))) lfloat;

__device__ __forceinline__ void load16(const float* g, float* l) {
    __builtin_amdgcn_global_load_lds((gfloat*)g, (lfloat*)l, 16, 0, 0);
}

__global__ __launch_bounds__(256, 2)
void wkv_fused(const float* __restrict__ td,
               const float* __restrict__ tf,
               const float* __restrict__ k,
               const float* __restrict__ v,
               float* __restrict__ y,
               int C)
{
    __shared__ float lds[2 * VOFF];                       // 67584 B
    __shared__ float sAA[NCHK][CHB], sBB[NCHK][CHB], sPP[NCHK][CHB]; // 3 KB

    const int tid   = threadIdx.x;
    const int ntile = C / CHB;
    const int b     = blockIdx.x / ntile;
    const int c0    = (blockIdx.x % ntile) * CHB;

    // ---- DMA phase: 64 async 1KB transfers (16 per wave) ----
    {
        const int wave = tid >> 6;
        const int lane = tid & 63;
        const size_t base0 = (size_t)b * T_FIX * C + c0;  // float offset of (b,0,c0)
        #pragma unroll
        for (int i = 0; i < 16; ++i) {
            int idx    = wave * 16 + i;    // 0..63
            int tensor = idx & 1;
            int chk    = idx >> 1;
            int t      = chk * CHL + (lane >> 1);
            int q      = lane & 1;          // which float4 within the 8-ch row
            const float* g = (tensor ? v : k) + base0 + (size_t)t * C + q * 4;
            float*       l = lds + tensor * VOFF + chk * CHUNK_F;  // wave-uniform base
            load16(g, l);                   // lane data lands at base + lane*16B
        }
    }

    const int ch  = tid & (CHB - 1);
    const int chk = tid >> 3;              // 0..31

    const float w = -__expf(td[c0 + ch]);
    const float u = tf[c0 + ch];

    __syncthreads();   // vmcnt(0) drain: LDS tile valid

    // ---- phase 1: local scan of own chunk from identity ----
    float aa = 0.f, bb = 0.f, pp = -1e38f;
    {
        const float* kl = lds + chk * CHUNK_F + ch;
        const float* vl = kl + VOFF;
        #pragma unroll
        for (int s = 0; s < CHL; ++s) {
            float kt = kl[s * CHB];
            float vt = vl[s * CHB];
            float ww2 = pp + w;
            float q2  = fmaxf(ww2, kt);
            float e1  = __expf(ww2 - q2);
            float e2  = __expf(kt - q2);
            aa = fmaf(e1, aa, e2 * vt);
            bb = fmaf(e1, bb, e2);
            pp = q2;
        }
    }
    sAA[chk][ch] = aa; sBB[chk][ch] = bb; sPP[chk][ch] = pp;
    __syncthreads();

    // ---- phase 2: serial combine per channel; leave prefix (initial state)
    //      for each chunk in place. Lane tid<8 handles channel ch==tid.
    if (tid < CHB) {
        float paa = 0.f, pbb = 0.f, ppp = -1e38f;
        const float Lw = (float)CHL * w;   // w of channel tid (ch==tid here)
        #pragma unroll 4
        for (int j = 0; j < NCHK; ++j) {
            float ca = sAA[j][tid], cb = sBB[j][tid], cm = sPP[j][tid];
            sAA[j][tid] = paa; sBB[j][tid] = pbb; sPP[j][tid] = ppp;
            float ppd = ppp + Lw;
            float pn  = fmaxf(ppd, cm);
            float ea  = __expf(ppd - pn);
            float eb  = __expf(cm - pn);
            paa = fmaf(ea, paa, eb * ca);
            pbb = fmaf(ea, pbb, eb * cb);
            ppp = pn;
        }
    }
    __syncthreads();

    // ---- phase 3: rescan with true initial state, emit y ----
    aa = sAA[chk][ch]; bb = sBB[chk][ch]; pp = sPP[chk][ch];
    {
        const float* kl = lds + chk * CHUNK_F + ch;
        const float* vl = kl + VOFF;
        float* yp = y + (size_t)(b * T_FIX + chk * CHL) * C + c0 + ch;
        #pragma unroll
        for (int s = 0; s < CHL; ++s) {
            float kt = kl[s * CHB];
            float vt = vl[s * CHB];
            float ww = u + kt;
            float q  = fmaxf(pp, ww);
            float e1 = __expf(pp - q);
            float e2 = __expf(ww - q);
            yp[(size_t)s * C] = __fdividef(fmaf(e1, aa, e2 * vt),
                                           fmaf(e1, bb, e2));
            float ww2 = pp + w;
            float q2  = fmaxf(ww2, kt);
            float e1b = __expf(ww2 - q2);
            float e2b = __expf(kt - q2);
            aa = fmaf(e1b, aa, e2b * vt);
            bb = fmaf(e1b, bb, e2b);
            pp = q2;
        }
    }
}

extern "C" void kernel_launch(void* const* d_in, const int* in_sizes, int n_in,
                              void* d_out, int out_size, void* d_ws, size_t ws_size,
                              hipStream_t stream)
{
    const float* td = (const float*)d_in[3];
    const float* tf = (const float*)d_in[4];
    const float* k  = (const float*)d_in[5];
    const float* v  = (const float*)d_in[6];
    float*       y  = (float*)d_out;

    const int C   = in_sizes[3];
    const int BTC = in_sizes[5];
    const int B   = BTC / (T_FIX * C);

    const int grid = B * (C / CHB);        // 8 * 256 = 2048 blocks

    wkv_fused<<<grid, 256, 0, stream>>>(td, tf, k, v, y, C);
}